// Round 9
// baseline (1274.162 us; speedup 1.0000x reference)
//
#include <hip/hip_runtime.h>
#include <hip/hip_bf16.h>
#include <math.h>

#define B_ 256
#define T_ 32
#define D_ 500
#define H_ 1024
#define V_ 8000
#define NF_ 512
#define G3H (3*H_)   // 3072
#define G6H (6*H_)   // 6144 (merged fwd+bwd gate row)
#define H2 (2*H_)    // 2048
#define OUTC (H_ + 3*NF_ + V_)   // 10560
#define KPAD 512     // D_ padded to 512 for 16B-aligned bf16 rows
#define NTAP 9
#define NCAT (NTAP*NF_)  // 4608
#define MS 512           // stacked M for recurrence (fwd 0..255, bwd 256..511)
#define WFRAG_G (64*32*512)   // elements per gate in whh frag layout (1,048,576)

typedef float f32x4 __attribute__((ext_vector_type(4)));
typedef short bf16x8 __attribute__((ext_vector_type(8)));

static __device__ __forceinline__ short f2b(float f) {
    unsigned u = __float_as_uint(f);
    unsigned r = (u + 0x7fffu + ((u >> 16) & 1u)) >> 16;
    return (short)r;
}
static __device__ __forceinline__ float b2f(short s) {
    return __uint_as_float(((unsigned)(unsigned short)s) << 16);
}

// ---------------------------------------------------------------------------
// bf16 MFMA GEMM (m97 structure + XCD swizzle): C[m,n] = sum_k A[m,k]*Bt[n,k]
// mode 0: fp32 C[m*ldc+n] = v + bias[n]
// mode 2: bf16 C[m*ldc+n] = bf16(v + bias[n])
// mode 3: fp16 C[m*ldc+n] = fp16(v)  (tap partials, NON-TEMPORAL store)
// Requires gridDim.x*gridDim.y % 8 == 0.
// ---------------------------------------------------------------------------
__global__ __launch_bounds__(256) void gemm_bt(
    const short* __restrict__ A, int lda,
    const short* __restrict__ Bt, int ldb,
    const float* __restrict__ bias,
    void* __restrict__ Cv, int ldc,
    int K, int mode)
{
    __shared__ short As[128 * 32];
    __shared__ short Bs[128 * 32];
    const int tid  = threadIdx.x;
    const int w    = tid >> 6, lane = tid & 63;

    // XCD-aware bijective swizzle (nwg % 8 == 0 at every call site)
    const int nbx = gridDim.x;
    const int nwg = nbx * gridDim.y;
    int flat = blockIdx.y * nbx + blockIdx.x;
    flat = (flat & 7) * (nwg >> 3) + (flat >> 3);
    const int m0 = (flat / nbx) * 128, n0 = (flat % nbx) * 128;

    const int wm   = (w >> 1) * 64, wn = (w & 1) * 64;

    f32x4 acc[4][4];
#pragma unroll
    for (int i = 0; i < 4; ++i)
#pragma unroll
        for (int j = 0; j < 4; ++j) acc[i][j] = (f32x4){0.f, 0.f, 0.f, 0.f};

    const int srow = w * 16 + (lane >> 2);
    const int scol = (lane & 3) * 8;
    const long aoff0 = (long)(m0 + srow) * lda + scol;
    const long aoff1 = (long)(m0 + srow + 64) * lda + scol;
    const long boff0 = (long)(n0 + srow) * ldb + scol;
    const long boff1 = (long)(n0 + srow + 64) * ldb + scol;
    short* lA0 = As + w * 512;        short* lA1 = As + 2048 + w * 512;
    short* lB0 = Bs + w * 512;        short* lB1 = Bs + 2048 + w * 512;

    const int fr = lane & 15, fk = (lane >> 4) * 8;

    for (int kt = 0; kt < K; kt += 32) {
        __builtin_amdgcn_global_load_lds((const __attribute__((address_space(1))) void*)(A + aoff0 + kt),
                                         (__attribute__((address_space(3))) void*)lA0, 16, 0, 0);
        __builtin_amdgcn_global_load_lds((const __attribute__((address_space(1))) void*)(A + aoff1 + kt),
                                         (__attribute__((address_space(3))) void*)lA1, 16, 0, 0);
        __builtin_amdgcn_global_load_lds((const __attribute__((address_space(1))) void*)(Bt + boff0 + kt),
                                         (__attribute__((address_space(3))) void*)lB0, 16, 0, 0);
        __builtin_amdgcn_global_load_lds((const __attribute__((address_space(1))) void*)(Bt + boff1 + kt),
                                         (__attribute__((address_space(3))) void*)lB1, 16, 0, 0);
        __syncthreads();
        bf16x8 af[4], bfv[4];
#pragma unroll
        for (int i = 0; i < 4; ++i) af[i]  = *(const bf16x8*)(As + (wm + i * 16 + fr) * 32 + fk);
#pragma unroll
        for (int j = 0; j < 4; ++j) bfv[j] = *(const bf16x8*)(Bs + (wn + j * 16 + fr) * 32 + fk);
#pragma unroll
        for (int i = 0; i < 4; ++i)
#pragma unroll
            for (int j = 0; j < 4; ++j)
                acc[i][j] = __builtin_amdgcn_mfma_f32_16x16x32_bf16(af[i], bfv[j], acc[i][j], 0, 0, 0);
        __syncthreads();
    }

    const int er = (lane >> 4) * 4;   // C/D: col = lane&15, row = (lane>>4)*4 + q
    const int ec = lane & 15;
#pragma unroll
    for (int i = 0; i < 4; ++i) {
#pragma unroll
        for (int j = 0; j < 4; ++j) {
#pragma unroll
            for (int q = 0; q < 4; ++q) {
                const int m = m0 + wm + i * 16 + er + q;
                const int n = n0 + wn + j * 16 + ec;
                float v = acc[i][j][q];
                if (mode == 0) {
                    ((float*)Cv)[(long)m * ldc + n] = v + bias[n];
                } else if (mode == 2) {
                    ((short*)Cv)[(long)m * ldc + n] = f2b(v + bias[n]);
                } else {
                    __builtin_nontemporal_store((_Float16)v, (_Float16*)Cv + (long)m * ldc + n);
                }
            }
        }
    }
}

// ---------------------------------------------------------------------------
// Repack Whh (fp32 [3H, H]) into global MFMA B-fragment layout:
// dst[((g*64 + j16)*32 + kt)*512 + l*8 + e] = bf16(Whh[g*1024 + j16*16 + (l&15)][kt*32 + (l>>4)*8 + e])
// ---------------------------------------------------------------------------
__global__ void repack_whh(const float* __restrict__ src, short* __restrict__ dst)
{
    const int idx = blockIdx.x * 256 + threadIdx.x;   // 3*64*32*64 = 393216
    const int l = idx & 63;
    const int kt = (idx >> 6) & 31;
    const int j16 = (idx >> 11) & 63;
    const int g = idx >> 17;
    const long srow = ((long)(g << 10) + (j16 << 4) + (l & 15)) * H_ + kt * 32 + ((l >> 4) << 3);
    short o[8];
#pragma unroll
    for (int e = 0; e < 8; ++e) o[e] = f2b(src[srow + e]);
    *(bf16x8*)&dst[(long)idx * 8] = *(bf16x8*)o;
}

// ---------------------------------------------------------------------------
// One GRU timestep, both dirs stacked; NO LDS, NO barriers. 256 blocks (r7
// geometry). bid: jt = bid&31 (XCD = jt%8, stable across launches -> whh
// frags stay L2-resident), mtd = bid>>5 -> dir = mtd>>2, mt = mtd&3.
// Block = 64m x 32j x 3 gates; 4 waves = 2x2 of (32m x 16j).
// A-frags gathered from plain h_bf; B-frags lane-linear from whh_frag.
// Epilogue-independent loads (xg, h32, lengths) are issued BEFORE the K-loop
// so their HBM/L3 latency hides under the 192 MFMAs.
// ---------------------------------------------------------------------------
__global__ __launch_bounds__(256) void gru_step_frag(
    const short* __restrict__ hbf_prev, short* __restrict__ hbf_next,
    const float* __restrict__ h32_prev, float* __restrict__ h32_next,
    const short* __restrict__ wfragf, const short* __restrict__ wfragb,
    const float* __restrict__ bhhf, const float* __restrict__ bhhb,
    const short* __restrict__ xgcat,
    short* __restrict__ gout, const int* __restrict__ lengths, int s)
{
    const int tid = threadIdx.x;
    const int w = tid >> 6, lane = tid & 63;
    const int bid = blockIdx.x;
    const int jt = bid & 31;
    const int mtd = bid >> 5;            // 0..7
    const int dir = mtd >> 2, mt = mtd & 3;
    const int m0 = dir * 256 + mt * 64;
    const int j0 = jt * 32;
    const int wm = (w >> 1) * 32, wj = (w & 1) * 16;
    const int tt = dir ? (T_ - 1 - s) : s;

    const short* wfrag = dir ? wfragb : wfragf;
    const float* bhh = dir ? bhhb : bhhf;

    const int fr15 = lane & 15, fk8 = (lane >> 4) * 8;
    const long arow0 = (long)(m0 + wm + fr15) * H_ + fk8;
    const long arow1 = arow0 + (long)16 * H_;
    const int j16 = (j0 + wj) >> 4;      // 0..63
    const short* bbase = wfrag + ((long)j16 * 32) * 512 + lane * 8;

    const int er = (lane >> 4) * 4, ec = lane & 15;
    const int jj = j0 + wj + ec;

    // ---- early independent loads (hide latency under the K-loop) ----
    float xr[2][4], xz[2][4], xn[2][4], hp[2][4];
    int lenv[2][4];
#pragma unroll
    for (int i = 0; i < 2; ++i) {
#pragma unroll
        for (int q = 0; q < 4; ++q) {
            const int m = m0 + wm + i * 16 + er + q;
            const int b = m & 255;
            const short* xrow = xgcat + ((long)b * T_ + tt) * G6H + (long)dir * G3H;
            xr[i][q] = b2f(xrow[jj]);
            xz[i][q] = b2f(xrow[H_ + jj]);
            xn[i][q] = b2f(xrow[2 * H_ + jj]);
            hp[i][q] = h32_prev[(long)m * H_ + jj];
            lenv[i][q] = lengths[b];
        }
    }
    const float bhr = bhh[jj], bhz = bhh[H_ + jj], bhn = bhh[2 * H_ + jj];

    f32x4 acc[3][2];
#pragma unroll
    for (int g = 0; g < 3; ++g)
#pragma unroll
        for (int i = 0; i < 2; ++i) acc[g][i] = (f32x4){0.f, 0.f, 0.f, 0.f};

#pragma unroll 4
    for (int kt = 0; kt < 32; ++kt) {
        const bf16x8 af0 = *(const bf16x8*)(hbf_prev + arow0 + kt * 32);
        const bf16x8 af1 = *(const bf16x8*)(hbf_prev + arow1 + kt * 32);
        const bf16x8 b0 = *(const bf16x8*)(bbase + (long)kt * 512);
        const bf16x8 b1 = *(const bf16x8*)(bbase + (long)kt * 512 + WFRAG_G);
        const bf16x8 b2 = *(const bf16x8*)(bbase + (long)kt * 512 + 2 * WFRAG_G);
        acc[0][0] = __builtin_amdgcn_mfma_f32_16x16x32_bf16(af0, b0, acc[0][0], 0, 0, 0);
        acc[0][1] = __builtin_amdgcn_mfma_f32_16x16x32_bf16(af1, b0, acc[0][1], 0, 0, 0);
        acc[1][0] = __builtin_amdgcn_mfma_f32_16x16x32_bf16(af0, b1, acc[1][0], 0, 0, 0);
        acc[1][1] = __builtin_amdgcn_mfma_f32_16x16x32_bf16(af1, b1, acc[1][1], 0, 0, 0);
        acc[2][0] = __builtin_amdgcn_mfma_f32_16x16x32_bf16(af0, b2, acc[2][0], 0, 0, 0);
        acc[2][1] = __builtin_amdgcn_mfma_f32_16x16x32_bf16(af1, b2, acc[2][1], 0, 0, 0);
    }

#pragma unroll
    for (int i = 0; i < 2; ++i) {
#pragma unroll
        for (int q = 0; q < 4; ++q) {
            const int m = m0 + wm + i * 16 + er + q;
            const int b = m & 255;
            const float rr = 1.f / (1.f + expf(-(xr[i][q] + acc[0][i][q] + bhr)));
            const float zz = 1.f / (1.f + expf(-(xz[i][q] + acc[1][i][q] + bhz)));
            const float nn = tanhf(xn[i][q] + rr * (acc[2][i][q] + bhn));
            const float hnew = (1.f - zz) * nn + zz * hp[i][q];
            const bool valid = tt < lenv[i][q];
            const float ho = valid ? hnew : hp[i][q];
            const long hidx = (long)m * H_ + jj;
            h32_next[hidx] = ho;
            hbf_next[hidx] = f2b(ho);
            gout[((long)b * T_ + tt) * H2 + (long)dir * H_ + jj] = valid ? f2b(hnew) : (short)0;
        }
    }
}

// fp32 -> bf16 with optional K padding (c >= Ksrc -> 0)
__global__ void f2b_pad(const float* __restrict__ src, short* __restrict__ dst,
                        int Ksrc, int Kdst)
{
    const int idx = blockIdx.x * 256 + threadIdx.x;
    const int r = idx / Kdst, c = idx % Kdst;
    dst[idx] = (c < Ksrc) ? f2b(src[(long)r * Ksrc + c]) : (short)0;
}

// concat two fp32 bias vectors [3072]+[3072] -> [6144]
__global__ void cat_bias(const float* __restrict__ a, const float* __restrict__ b,
                         float* __restrict__ dst)
{
    const int idx = blockIdx.x * 256 + threadIdx.x;   // 6144
    dst[idx] = (idx < G3H) ? a[idx] : b[idx - G3H];
}

// conv weight repack: dst[k][f][c] = bf16(src[f][c][k]), src [NF_,2H,ws]
__global__ void repack_tap(const float* __restrict__ src, short* __restrict__ dst, int ws)
{
    const int idx = blockIdx.x * 256 + threadIdx.x;
    const int rem = idx % (NF_ * H2);
    const int k = idx / (NF_ * H2);
    const int f = rem >> 11, c = rem & 2047;
    dst[idx] = f2b(src[((long)(f << 11) + c) * ws + k]);
}

// mean over valid timesteps (gout is zero past length), bf16 in, bf16 out
__global__ void mean_pool2(const short* __restrict__ gin,
                           const int* __restrict__ lengths,
                           short* __restrict__ mean_bf)
{
    const int idx = blockIdx.x * 256 + threadIdx.x;   // B*2H
    const int b = idx >> 11, c = idx & 2047;
    float s = 0.f;
#pragma unroll
    for (int t = 0; t < T_; ++t) s += b2f(gin[((long)(b * T_ + t)) * H2 + c]);
    mean_bf[idx] = f2b(s / (float)lengths[b]);
}

// shifted tap-sum + bias + leaky-relu + max over time
__global__ void conv_max(const _Float16* __restrict__ P,
                         const float* __restrict__ cb2, const float* __restrict__ cb3,
                         const float* __restrict__ cb4, float* __restrict__ out)
{
    const int idx = blockIdx.x * 256 + threadIdx.x;   // B*1536
    const int b = idx / 1536, u0 = idx % 1536;
    int Tout, ws, base, f; float bias;
    if (u0 < 512)       { ws = 2; Tout = 33; base = 0;    f = u0;        bias = cb2[f]; }
    else if (u0 < 1024) { ws = 3; Tout = 34; base = 1024; f = u0 - 512;  bias = cb3[f]; }
    else                { ws = 4; Tout = 35; base = 2560; f = u0 - 1024; bias = cb4[f]; }
    const _Float16* Pb = P + (long)b * T_ * NCAT + base + f;
    float m = -INFINITY;
    for (int u = 0; u < Tout; ++u) {
        float s = bias;
        for (int k = 0; k < ws; ++k) {
            const int t = u - (ws - 1) + k;
            if (t >= 0 && t < T_) s += (float)Pb[(long)t * NCAT + k * NF_];
        }
        s = s > 0.f ? s : 0.01f * s;
        m = fmaxf(m, s);
    }
    out[(long)b * OUTC + H_ + u0] = m;
}

__global__ void bow_copy(const float* __restrict__ bow, float* __restrict__ out)
{
    const int idx = blockIdx.x * 256 + threadIdx.x;   // B * 2000 float4s
    const int b = idx / 2000, q = idx % 2000;
    const float4* src = (const float4*)(bow + (long)b * V_);
    float4* dst = (float4*)(out + (long)b * OUTC + H_ + 3 * NF_);
    dst[q] = src[q];
}

extern "C" void kernel_launch(void* const* d_in, const int* in_sizes, int n_in,
                              void* d_out, int out_size, void* d_ws, size_t ws_size,
                              hipStream_t stream)
{
    const float* text    = (const float*)d_in[0];
    const float* bow     = (const float*)d_in[1];
    const int*   lengths = (const int*)  d_in[2];
    const float* Wih_f   = (const float*)d_in[3];
    const float* Whh_f   = (const float*)d_in[4];
    const float* bih_f   = (const float*)d_in[5];
    const float* bhh_f   = (const float*)d_in[6];
    const float* Wih_b   = (const float*)d_in[7];
    const float* Whh_b   = (const float*)d_in[8];
    const float* bih_b   = (const float*)d_in[9];
    const float* bhh_b   = (const float*)d_in[10];
    const float* W_red   = (const float*)d_in[11];
    const float* b_red   = (const float*)d_in[12];
    const float* cw2     = (const float*)d_in[13];
    const float* cb2     = (const float*)d_in[14];
    const float* cw3     = (const float*)d_in[15];
    const float* cb3     = (const float*)d_in[16];
    const float* cw4     = (const float*)d_in[17];
    const float* cb4     = (const float*)d_in[18];
    float* out = (float*)d_out;

    // ---- workspace layout ----
    char* ws = (char*)d_ws;
    size_t off = 0;
    short* xgcat = (short*)(ws + off); off += (size_t)B_ * T_ * G6H * 2;  // 100.66 MB
    _Float16* P    = (_Float16*)(char*)xgcat;                             // overlay (conv phase)
    short* wtap_bf = (short*)((char*)xgcat + (size_t)B_ * T_ * NCAT * 2); // after P
    short* gin_bf = (short*)(ws + off); off += (size_t)B_ * T_ * H2 * 2;  // 33.55 MB
    short* text_bf = gin_bf;                                              // overlay (proj phase)
    short* wihf_bf = (short*)((char*)gin_bf + (size_t)B_ * T_ * KPAD * 2);
    short* wihb_bf = wihf_bf + (size_t)G3H * KPAD;   // contiguous with wihf (merged B)
    short* wfragf  = (short*)(ws + off); off += (size_t)3 * WFRAG_G * 2;  // 6.3 MB
    short* wfragb  = (short*)(ws + off); off += (size_t)3 * WFRAG_G * 2;  // 6.3 MB
    short* wred_bf = (short*)(ws + off); off += (size_t)H_ * H2 * 2;
    float* h32     = (float*)(ws + off); off += (size_t)2 * MS * H_ * 4;  // ping-pong fp32
    short* h_bf    = (short*)(ws + off); off += (size_t)2 * MS * H_ * 2;  // ping-pong bf16
    short* gmean_bf= (short*)(ws + off); off += (size_t)B_ * H2 * 2;
    float* bih_cat = (float*)(ws + off); off += (size_t)G6H * 4;

    const dim3 blk(256);

    // ---- conversions / repacks ----
    f2b_pad<<<dim3((B_ * T_ * KPAD) / 256), blk, 0, stream>>>(text, text_bf, D_, KPAD);
    f2b_pad<<<dim3((G3H * KPAD) / 256), blk, 0, stream>>>(Wih_f, wihf_bf, D_, KPAD);
    f2b_pad<<<dim3((G3H * KPAD) / 256), blk, 0, stream>>>(Wih_b, wihb_bf, D_, KPAD);
    f2b_pad<<<dim3((H_ * H2) / 256), blk, 0, stream>>>(W_red, wred_bf, H2, H2);
    cat_bias<<<dim3(G6H / 256), blk, 0, stream>>>(bih_f, bih_b, bih_cat);
    repack_whh<<<dim3(1536), blk, 0, stream>>>(Whh_f, wfragf);
    repack_whh<<<dim3(1536), blk, 0, stream>>>(Whh_b, wfragb);

    // ---- merged input projection (both directions, N=6144) ----
    gemm_bt<<<dim3(G6H / 128, (B_ * T_) / 128), blk, 0, stream>>>(
        text_bf, KPAD, wihf_bf, KPAD, bih_cat, xgcat, G6H, KPAD, 2);

    // ---- stacked bidirectional recurrence: 32 per-step launches ----
    hipMemsetAsync(h32, 0, (size_t)MS * H_ * 4, stream);   // h32 buf0 = 0
    hipMemsetAsync(h_bf, 0, (size_t)MS * H_ * 2, stream);  // h_bf buf0 = 0
    for (int s = 0; s < T_; ++s) {
        const int cur = s & 1, nxt = (s + 1) & 1;
        gru_step_frag<<<dim3(256), blk, 0, stream>>>(
            h_bf + (size_t)cur * MS * H_, h_bf + (size_t)nxt * MS * H_,
            h32 + (size_t)cur * MS * H_, h32 + (size_t)nxt * MS * H_,
            wfragf, wfragb, bhh_f, bhh_b, xgcat,
            gin_bf, lengths, s);
    }

    // ---- pooled linear head ----
    mean_pool2<<<dim3((B_ * H2) / 256), blk, 0, stream>>>(gin_bf, lengths, gmean_bf);
    gemm_bt<<<dim3(H_ / 128, B_ / 128), blk, 0, stream>>>(
        gmean_bf, H2, wred_bf, H2, b_red, out, OUTC, H2, 0);

    // ---- conv: repack taps (xg dead), one big GEMM -> fp16 partials ----
    repack_tap<<<dim3((2 * NF_ * H2) / 256), blk, 0, stream>>>(cw2, wtap_bf, 2);
    repack_tap<<<dim3((3 * NF_ * H2) / 256), blk, 0, stream>>>(cw3, wtap_bf + (size_t)2 * NF_ * H2, 3);
    repack_tap<<<dim3((4 * NF_ * H2) / 256), blk, 0, stream>>>(cw4, wtap_bf + (size_t)5 * NF_ * H2, 4);
    gemm_bt<<<dim3(NCAT / 128, (B_ * T_) / 128), blk, 0, stream>>>(
        gin_bf, H2, wtap_bf, H2, nullptr, P, NCAT, H2, 3);

    conv_max<<<dim3((B_ * 1536) / 256), blk, 0, stream>>>(P, cb2, cb3, cb4, out);
    bow_copy<<<dim3((B_ * 2000) / 256), blk, 0, stream>>>(bow, out);
}

// Round 10
// 1097.660 us; speedup vs baseline: 1.1608x; 1.1608x over previous
//
#include <hip/hip_runtime.h>
#include <hip/hip_bf16.h>
#include <math.h>

#define B_ 256
#define T_ 32
#define D_ 500
#define H_ 1024
#define V_ 8000
#define NF_ 512
#define G3H (3*H_)   // 3072
#define H2 (2*H_)    // 2048
#define OUTC (H_ + 3*NF_ + V_)   // 10560
#define KPAD 512     // D_ padded to 512 for 16B-aligned bf16 rows
#define NTAP 9
#define NCAT (NTAP*NF_)  // 4608
#define MS 512           // stacked M for recurrence (fwd 0..255, bwd 256..511)
#define WFRAG_G (64*32*512)   // elements per gate in whh frag layout (1,048,576)

typedef float f32x4 __attribute__((ext_vector_type(4)));
typedef short bf16x8 __attribute__((ext_vector_type(8)));

static __device__ __forceinline__ short f2b(float f) {
    unsigned u = __float_as_uint(f);
    unsigned r = (u + 0x7fffu + ((u >> 16) & 1u)) >> 16;
    return (short)r;
}
static __device__ __forceinline__ float b2f(short s) {
    return __uint_as_float(((unsigned)(unsigned short)s) << 16);
}

// ---------------------------------------------------------------------------
// 256x256-tile bf16 GEMM, counted-vmcnt pipeline (T3+T4+T5, no swizzle).
// C[m,n] = sum_k A[m,k] * Bt[n,k]. 512 threads = 8 waves (2M x 4N),
// per-wave output 128x64. BK=32, 4 LDS buffers, 3-tile-deep prefetch,
// vmcnt(8) steady-state (4 loads/wave/tile), 2 phases x 16 MFMA per tile.
// MODE 2: bf16 C = bf16(v + bias[n]);  MODE 3: fp16 C = v.
// M,N multiples of 256; K multiple of 32, K/32 >= 4. Grid nwg % 8 == 0.
// ---------------------------------------------------------------------------
template<int MODE>
__global__ __launch_bounds__(512) void gemm256(
    const short* __restrict__ A, int lda,
    const short* __restrict__ Bt, int ldb,
    const float* __restrict__ bias,
    void* __restrict__ Cv, int ldc, int K)
{
    __shared__ short As[4][256 * 32];
    __shared__ short Bs[4][256 * 32];
    const int tid = threadIdx.x;
    const int w = tid >> 6, lane = tid & 63;

    // XCD-aware bijective swizzle
    const int nbx = gridDim.x;
    const int nwg = nbx * gridDim.y;
    int flat = blockIdx.y * nbx + blockIdx.x;
    flat = (flat & 7) * (nwg >> 3) + (flat >> 3);
    const int m0 = (flat / nbx) * 256, n0 = (flat % nbx) * 256;

    const int wm = (w >> 2) * 128;       // 0 or 128
    const int wn = (w & 3) * 64;         // 0,64,128,192

    // staging: issue i in {0,1}; wave w covers rows i*128 + w*16 + (lane>>2)
    const int srow = w * 16 + (lane >> 2);
    const int scol = (lane & 3) * 8;
    const long aoff = (long)(m0 + srow) * lda + scol;
    const long boff = (long)(n0 + srow) * ldb + scol;

#define STAGE256(t_, buf_) do { \
    const long ka_ = (long)(t_) * 32; \
    __builtin_amdgcn_global_load_lds((const __attribute__((address_space(1))) void*)(A + aoff + ka_), \
        (__attribute__((address_space(3))) void*)(&As[buf_][w * 512]), 16, 0, 0); \
    __builtin_amdgcn_global_load_lds((const __attribute__((address_space(1))) void*)(A + aoff + (long)128 * lda + ka_), \
        (__attribute__((address_space(3))) void*)(&As[buf_][4096 + w * 512]), 16, 0, 0); \
    __builtin_amdgcn_global_load_lds((const __attribute__((address_space(1))) void*)(Bt + boff + ka_), \
        (__attribute__((address_space(3))) void*)(&Bs[buf_][w * 512]), 16, 0, 0); \
    __builtin_amdgcn_global_load_lds((const __attribute__((address_space(1))) void*)(Bt + boff + (long)128 * ldb + ka_), \
        (__attribute__((address_space(3))) void*)(&Bs[buf_][4096 + w * 512]), 16, 0, 0); \
} while (0)

    f32x4 acc[8][4];
#pragma unroll
    for (int i = 0; i < 8; ++i)
#pragma unroll
        for (int j = 0; j < 4; ++j) acc[i][j] = (f32x4){0.f, 0.f, 0.f, 0.f};

    const int fr = lane & 15, fk = (lane >> 4) * 8;
    const int T = K >> 5;   // #K-tiles, >= 4

    // prologue: 3-deep prefetch
    STAGE256(0, 0);
    STAGE256(1, 1);
    STAGE256(2, 2);
    asm volatile("s_waitcnt vmcnt(8)" ::: "memory");   // tile 0 landed (my wave)
    asm volatile("s_barrier" ::: "memory");            // all waves

    for (int t = 0; t < T; ++t) {
        const int buf = t & 3;
        if (t + 3 < T) STAGE256(t + 3, (t + 3) & 3);

        // ---- phase A: m-frags 0..3, all b-frags ----
        bf16x8 af[4], bfv[4];
#pragma unroll
        for (int i = 0; i < 4; ++i)
            af[i] = *(const bf16x8*)(&As[buf][(wm + i * 16 + fr) * 32 + fk]);
#pragma unroll
        for (int j = 0; j < 4; ++j)
            bfv[j] = *(const bf16x8*)(&Bs[buf][(wn + j * 16 + fr) * 32 + fk]);
        __builtin_amdgcn_s_setprio(1);
#pragma unroll
        for (int i = 0; i < 4; ++i)
#pragma unroll
            for (int j = 0; j < 4; ++j)
                acc[i][j] = __builtin_amdgcn_mfma_f32_16x16x32_bf16(af[i], bfv[j], acc[i][j], 0, 0, 0);
        __builtin_amdgcn_s_setprio(0);
        asm volatile("s_barrier" ::: "memory");

        // ---- phase B: m-frags 4..7 ----
#pragma unroll
        for (int i = 0; i < 4; ++i)
            af[i] = *(const bf16x8*)(&As[buf][(wm + 64 + i * 16 + fr) * 32 + fk]);
        __builtin_amdgcn_s_setprio(1);
#pragma unroll
        for (int i = 0; i < 4; ++i)
#pragma unroll
            for (int j = 0; j < 4; ++j)
                acc[4 + i][j] = __builtin_amdgcn_mfma_f32_16x16x32_bf16(af[i], bfv[j], acc[4 + i][j], 0, 0, 0);
        __builtin_amdgcn_s_setprio(0);

        // end-of-iter: wait for tile t+1 (counted, never 0 mid-loop)
        if (t < T - 3)      asm volatile("s_waitcnt vmcnt(8)" ::: "memory");
        else if (t == T - 3) asm volatile("s_waitcnt vmcnt(4)" ::: "memory");
        else if (t == T - 2) asm volatile("s_waitcnt vmcnt(0)" ::: "memory");
        asm volatile("s_barrier" ::: "memory");
    }
#undef STAGE256

    const int er = (lane >> 4) * 4, ec = lane & 15;
#pragma unroll
    for (int i = 0; i < 8; ++i) {
#pragma unroll
        for (int j = 0; j < 4; ++j) {
#pragma unroll
            for (int q = 0; q < 4; ++q) {
                const int m = m0 + wm + i * 16 + er + q;
                const int n = n0 + wn + j * 16 + ec;
                const float v = acc[i][j][q];
                if (MODE == 2)
                    ((short*)Cv)[(long)m * ldc + n] = f2b(v + bias[n]);
                else
                    ((_Float16*)Cv)[(long)m * ldc + n] = (_Float16)v;
            }
        }
    }
}

// ---------------------------------------------------------------------------
// m97-structure 128x128 GEMM (kept for the small reduce GEMM). mode 0 only.
// ---------------------------------------------------------------------------
__global__ __launch_bounds__(256) void gemm_bt(
    const short* __restrict__ A, int lda,
    const short* __restrict__ Bt, int ldb,
    const float* __restrict__ bias,
    void* __restrict__ Cv, int ldc,
    int K, int mode)
{
    __shared__ short As[128 * 32];
    __shared__ short Bs[128 * 32];
    const int tid  = threadIdx.x;
    const int w    = tid >> 6, lane = tid & 63;

    const int nbx = gridDim.x;
    const int nwg = nbx * gridDim.y;
    int flat = blockIdx.y * nbx + blockIdx.x;
    flat = (flat & 7) * (nwg >> 3) + (flat >> 3);
    const int m0 = (flat / nbx) * 128, n0 = (flat % nbx) * 128;

    const int wm   = (w >> 1) * 64, wn = (w & 1) * 64;

    f32x4 acc[4][4];
#pragma unroll
    for (int i = 0; i < 4; ++i)
#pragma unroll
        for (int j = 0; j < 4; ++j) acc[i][j] = (f32x4){0.f, 0.f, 0.f, 0.f};

    const int srow = w * 16 + (lane >> 2);
    const int scol = (lane & 3) * 8;
    const long aoff0 = (long)(m0 + srow) * lda + scol;
    const long aoff1 = (long)(m0 + srow + 64) * lda + scol;
    const long boff0 = (long)(n0 + srow) * ldb + scol;
    const long boff1 = (long)(n0 + srow + 64) * ldb + scol;
    short* lA0 = As + w * 512;        short* lA1 = As + 2048 + w * 512;
    short* lB0 = Bs + w * 512;        short* lB1 = Bs + 2048 + w * 512;

    const int fr = lane & 15, fk = (lane >> 4) * 8;

    for (int kt = 0; kt < K; kt += 32) {
        __builtin_amdgcn_global_load_lds((const __attribute__((address_space(1))) void*)(A + aoff0 + kt),
                                         (__attribute__((address_space(3))) void*)lA0, 16, 0, 0);
        __builtin_amdgcn_global_load_lds((const __attribute__((address_space(1))) void*)(A + aoff1 + kt),
                                         (__attribute__((address_space(3))) void*)lA1, 16, 0, 0);
        __builtin_amdgcn_global_load_lds((const __attribute__((address_space(1))) void*)(Bt + boff0 + kt),
                                         (__attribute__((address_space(3))) void*)lB0, 16, 0, 0);
        __builtin_amdgcn_global_load_lds((const __attribute__((address_space(1))) void*)(Bt + boff1 + kt),
                                         (__attribute__((address_space(3))) void*)lB1, 16, 0, 0);
        __syncthreads();
        bf16x8 af[4], bfv[4];
#pragma unroll
        for (int i = 0; i < 4; ++i) af[i]  = *(const bf16x8*)(As + (wm + i * 16 + fr) * 32 + fk);
#pragma unroll
        for (int j = 0; j < 4; ++j) bfv[j] = *(const bf16x8*)(Bs + (wn + j * 16 + fr) * 32 + fk);
#pragma unroll
        for (int i = 0; i < 4; ++i)
#pragma unroll
            for (int j = 0; j < 4; ++j)
                acc[i][j] = __builtin_amdgcn_mfma_f32_16x16x32_bf16(af[i], bfv[j], acc[i][j], 0, 0, 0);
        __syncthreads();
    }

    const int er = (lane >> 4) * 4;
    const int ec = lane & 15;
#pragma unroll
    for (int i = 0; i < 4; ++i) {
#pragma unroll
        for (int j = 0; j < 4; ++j) {
#pragma unroll
            for (int q = 0; q < 4; ++q) {
                const int m = m0 + wm + i * 16 + er + q;
                const int n = n0 + wn + j * 16 + ec;
                float v = acc[i][j][q];
                if (mode == 0) {
                    ((float*)Cv)[(long)m * ldc + n] = v + bias[n];
                } else if (mode == 2) {
                    ((short*)Cv)[(long)m * ldc + n] = f2b(v + bias[n]);
                } else {
                    ((_Float16*)Cv)[(long)m * ldc + n] = (_Float16)v;
                }
            }
        }
    }
}

// ---------------------------------------------------------------------------
// Repack Whh (fp32 [3H, H]) into global MFMA B-fragment layout.
// ---------------------------------------------------------------------------
__global__ void repack_whh(const float* __restrict__ src, short* __restrict__ dst)
{
    const int idx = blockIdx.x * 256 + threadIdx.x;   // 3*64*32*64 = 393216
    const int l = idx & 63;
    const int kt = (idx >> 6) & 31;
    const int j16 = (idx >> 11) & 63;
    const int g = idx >> 17;
    const long srow = ((long)(g << 10) + (j16 << 4) + (l & 15)) * H_ + kt * 32 + ((l >> 4) << 3);
    short o[8];
#pragma unroll
    for (int e = 0; e < 8; ++e) o[e] = f2b(src[srow + e]);
    *(bf16x8*)&dst[(long)idx * 8] = *(bf16x8*)o;
}

// ---------------------------------------------------------------------------
// One GRU timestep (r7-proven): both dirs stacked; NO LDS, NO barriers.
// 256 blocks. Epilogue loads stay AFTER the K-loop (r9's hoist regressed).
// ---------------------------------------------------------------------------
__global__ __launch_bounds__(256) void gru_step_frag(
    const short* __restrict__ hbf_prev, short* __restrict__ hbf_next,
    const float* __restrict__ h32_prev, float* __restrict__ h32_next,
    const short* __restrict__ wfragf, const short* __restrict__ wfragb,
    const float* __restrict__ bhhf, const float* __restrict__ bhhb,
    const short* __restrict__ xgf, const short* __restrict__ xgb,
    short* __restrict__ gout, const int* __restrict__ lengths, int s)
{
    const int tid = threadIdx.x;
    const int w = tid >> 6, lane = tid & 63;
    const int bid = blockIdx.x;
    const int jt = bid & 31;
    const int mtd = bid >> 5;            // 0..7
    const int dir = mtd >> 2, mt = mtd & 3;
    const int m0 = dir * 256 + mt * 64;
    const int j0 = jt * 32;
    const int wm = (w >> 1) * 32, wj = (w & 1) * 16;
    const int tt = dir ? (T_ - 1 - s) : s;

    const short* wfrag = dir ? wfragb : wfragf;
    const float* bhh = dir ? bhhb : bhhf;
    const short* xg  = dir ? xgb : xgf;

    const int fr15 = lane & 15, fk8 = (lane >> 4) * 8;
    const long arow0 = (long)(m0 + wm + fr15) * H_ + fk8;
    const long arow1 = arow0 + (long)16 * H_;
    const int j16 = (j0 + wj) >> 4;      // 0..63
    const short* bbase = wfrag + ((long)j16 * 32) * 512 + lane * 8;

    f32x4 acc[3][2];
#pragma unroll
    for (int g = 0; g < 3; ++g)
#pragma unroll
        for (int i = 0; i < 2; ++i) acc[g][i] = (f32x4){0.f, 0.f, 0.f, 0.f};

#pragma unroll 4
    for (int kt = 0; kt < 32; ++kt) {
        const bf16x8 af0 = *(const bf16x8*)(hbf_prev + arow0 + kt * 32);
        const bf16x8 af1 = *(const bf16x8*)(hbf_prev + arow1 + kt * 32);
        const bf16x8 b0 = *(const bf16x8*)(bbase + (long)kt * 512);
        const bf16x8 b1 = *(const bf16x8*)(bbase + (long)kt * 512 + WFRAG_G);
        const bf16x8 b2 = *(const bf16x8*)(bbase + (long)kt * 512 + 2 * WFRAG_G);
        acc[0][0] = __builtin_amdgcn_mfma_f32_16x16x32_bf16(af0, b0, acc[0][0], 0, 0, 0);
        acc[0][1] = __builtin_amdgcn_mfma_f32_16x16x32_bf16(af1, b0, acc[0][1], 0, 0, 0);
        acc[1][0] = __builtin_amdgcn_mfma_f32_16x16x32_bf16(af0, b1, acc[1][0], 0, 0, 0);
        acc[1][1] = __builtin_amdgcn_mfma_f32_16x16x32_bf16(af1, b1, acc[1][1], 0, 0, 0);
        acc[2][0] = __builtin_amdgcn_mfma_f32_16x16x32_bf16(af0, b2, acc[2][0], 0, 0, 0);
        acc[2][1] = __builtin_amdgcn_mfma_f32_16x16x32_bf16(af1, b2, acc[2][1], 0, 0, 0);
    }

    const int er = (lane >> 4) * 4, ec = lane & 15;
    const int jj = j0 + wj + ec;
    const float bhr = bhh[jj], bhz = bhh[H_ + jj], bhn = bhh[2 * H_ + jj];

#pragma unroll
    for (int i = 0; i < 2; ++i) {
#pragma unroll
        for (int q = 0; q < 4; ++q) {
            const int m = m0 + wm + i * 16 + er + q;
            const int b = m & 255;
            const short* xrow = xg + ((long)b * T_ + tt) * G3H;
            const float xr = b2f(xrow[jj]);
            const float xz = b2f(xrow[H_ + jj]);
            const float xn = b2f(xrow[2 * H_ + jj]);
            const float rr = 1.f / (1.f + expf(-(xr + acc[0][i][q] + bhr)));
            const float zz = 1.f / (1.f + expf(-(xz + acc[1][i][q] + bhz)));
            const float nn = tanhf(xn + rr * (acc[2][i][q] + bhn));
            const long hidx = (long)m * H_ + jj;
            const float hp = h32_prev[hidx];
            const float hnew = (1.f - zz) * nn + zz * hp;
            const bool valid = tt < lengths[b];
            const float ho = valid ? hnew : hp;
            h32_next[hidx] = ho;
            hbf_next[hidx] = f2b(ho);
            gout[((long)b * T_ + tt) * H2 + (long)dir * H_ + jj] = valid ? f2b(hnew) : (short)0;
        }
    }
}

// fp32 -> bf16 with optional K padding (c >= Ksrc -> 0)
__global__ void f2b_pad(const float* __restrict__ src, short* __restrict__ dst,
                        int Ksrc, int Kdst)
{
    const int idx = blockIdx.x * 256 + threadIdx.x;
    const int r = idx / Kdst, c = idx % Kdst;
    dst[idx] = (c < Ksrc) ? f2b(src[(long)r * Ksrc + c]) : (short)0;
}

// conv weight repack: dst[k][f][c] = bf16(src[f][c][k]), src [NF_,2H,ws]
__global__ void repack_tap(const float* __restrict__ src, short* __restrict__ dst, int ws)
{
    const int idx = blockIdx.x * 256 + threadIdx.x;
    const int rem = idx % (NF_ * H2);
    const int k = idx / (NF_ * H2);
    const int f = rem >> 11, c = rem & 2047;
    dst[idx] = f2b(src[((long)(f << 11) + c) * ws + k]);
}

// mean over valid timesteps (gout is zero past length), bf16 in, bf16 out
__global__ void mean_pool2(const short* __restrict__ gin,
                           const int* __restrict__ lengths,
                           short* __restrict__ mean_bf)
{
    const int idx = blockIdx.x * 256 + threadIdx.x;   // B*2H
    const int b = idx >> 11, c = idx & 2047;
    float s = 0.f;
#pragma unroll
    for (int t = 0; t < T_; ++t) s += b2f(gin[((long)(b * T_ + t)) * H2 + c]);
    mean_bf[idx] = f2b(s / (float)lengths[b]);
}

// shifted tap-sum + bias + leaky-relu + max over time
__global__ void conv_max(const _Float16* __restrict__ P,
                         const float* __restrict__ cb2, const float* __restrict__ cb3,
                         const float* __restrict__ cb4, float* __restrict__ out)
{
    const int idx = blockIdx.x * 256 + threadIdx.x;   // B*1536
    const int b = idx / 1536, u0 = idx % 1536;
    int Tout, ws, base, f; float bias;
    if (u0 < 512)       { ws = 2; Tout = 33; base = 0;    f = u0;        bias = cb2[f]; }
    else if (u0 < 1024) { ws = 3; Tout = 34; base = 1024; f = u0 - 512;  bias = cb3[f]; }
    else                { ws = 4; Tout = 35; base = 2560; f = u0 - 1024; bias = cb4[f]; }
    const _Float16* Pb = P + (long)b * T_ * NCAT + base + f;
    float m = -INFINITY;
    for (int u = 0; u < Tout; ++u) {
        float s = bias;
        for (int k = 0; k < ws; ++k) {
            const int t = u - (ws - 1) + k;
            if (t >= 0 && t < T_) s += (float)Pb[(long)t * NCAT + k * NF_];
        }
        s = s > 0.f ? s : 0.01f * s;
        m = fmaxf(m, s);
    }
    out[(long)b * OUTC + H_ + u0] = m;
}

__global__ void bow_copy(const float* __restrict__ bow, float* __restrict__ out)
{
    const int idx = blockIdx.x * 256 + threadIdx.x;   // B * 2000 float4s
    const int b = idx / 2000, q = idx % 2000;
    const float4* src = (const float4*)(bow + (long)b * V_);
    float4* dst = (float4*)(out + (long)b * OUTC + H_ + 3 * NF_);
    dst[q] = src[q];
}

extern "C" void kernel_launch(void* const* d_in, const int* in_sizes, int n_in,
                              void* d_out, int out_size, void* d_ws, size_t ws_size,
                              hipStream_t stream)
{
    const float* text    = (const float*)d_in[0];
    const float* bow     = (const float*)d_in[1];
    const int*   lengths = (const int*)  d_in[2];
    const float* Wih_f   = (const float*)d_in[3];
    const float* Whh_f   = (const float*)d_in[4];
    const float* bih_f   = (const float*)d_in[5];
    const float* bhh_f   = (const float*)d_in[6];
    const float* Wih_b   = (const float*)d_in[7];
    const float* Whh_b   = (const float*)d_in[8];
    const float* bih_b   = (const float*)d_in[9];
    const float* bhh_b   = (const float*)d_in[10];
    const float* W_red   = (const float*)d_in[11];
    const float* b_red   = (const float*)d_in[12];
    const float* cw2     = (const float*)d_in[13];
    const float* cb2     = (const float*)d_in[14];
    const float* cw3     = (const float*)d_in[15];
    const float* cb3     = (const float*)d_in[16];
    const float* cw4     = (const float*)d_in[17];
    const float* cb4     = (const float*)d_in[18];
    float* out = (float*)d_out;

    // ---- workspace layout (r7) ----
    char* ws = (char*)d_ws;
    size_t off = 0;
    short* xg_f = (short*)(ws + off); off += (size_t)B_ * T_ * G3H * 2;   // 50.33 MB
    short* xg_b = (short*)(ws + off); off += (size_t)B_ * T_ * G3H * 2;   // 50.33 MB
    _Float16* P    = (_Float16*)(char*)xg_f;                              // overlay (conv phase)
    short* wtap_bf = (short*)((char*)xg_f + (size_t)B_ * T_ * NCAT * 2);  // after P
    short* gin_bf = (short*)(ws + off); off += (size_t)B_ * T_ * H2 * 2;  // 33.55 MB
    short* text_bf = gin_bf;                                              // overlay (proj phase)
    short* wihf_bf = (short*)((char*)gin_bf + (size_t)B_ * T_ * KPAD * 2);
    short* wihb_bf = wihf_bf + (size_t)G3H * KPAD;
    short* wfragf  = (short*)(ws + off); off += (size_t)3 * WFRAG_G * 2;  // 6.3 MB
    short* wfragb  = (short*)(ws + off); off += (size_t)3 * WFRAG_G * 2;  // 6.3 MB
    short* wred_bf = (short*)(ws + off); off += (size_t)H_ * H2 * 2;
    float* h32     = (float*)(ws + off); off += (size_t)2 * MS * H_ * 4;  // ping-pong fp32
    short* h_bf    = (short*)(ws + off); off += (size_t)2 * MS * H_ * 2;  // ping-pong bf16
    short* gmean_bf= (short*)(ws + off); off += (size_t)B_ * H2 * 2;

    const dim3 blk(256);

    // ---- conversions / repacks ----
    f2b_pad<<<dim3((B_ * T_ * KPAD) / 256), blk, 0, stream>>>(text, text_bf, D_, KPAD);
    f2b_pad<<<dim3((G3H * KPAD) / 256), blk, 0, stream>>>(Wih_f, wihf_bf, D_, KPAD);
    f2b_pad<<<dim3((G3H * KPAD) / 256), blk, 0, stream>>>(Wih_b, wihb_bf, D_, KPAD);
    f2b_pad<<<dim3((H_ * H2) / 256), blk, 0, stream>>>(W_red, wred_bf, H2, H2);
    repack_whh<<<dim3(1536), blk, 0, stream>>>(Whh_f, wfragf);
    repack_whh<<<dim3(1536), blk, 0, stream>>>(Whh_b, wfragb);

    // ---- input projections (both directions), 256^2 pipelined GEMM ----
    gemm256<2><<<dim3(G3H / 256, (B_ * T_) / 256), dim3(512), 0, stream>>>(
        text_bf, KPAD, wihf_bf, KPAD, bih_f, xg_f, G3H, KPAD);
    gemm256<2><<<dim3(G3H / 256, (B_ * T_) / 256), dim3(512), 0, stream>>>(
        text_bf, KPAD, wihb_bf, KPAD, bih_b, xg_b, G3H, KPAD);

    // ---- stacked bidirectional recurrence: 32 per-step launches (r7) ----
    hipMemsetAsync(h32, 0, (size_t)MS * H_ * 4, stream);   // h32 buf0 = 0
    hipMemsetAsync(h_bf, 0, (size_t)MS * H_ * 2, stream);  // h_bf buf0 = 0
    for (int s = 0; s < T_; ++s) {
        const int cur = s & 1, nxt = (s + 1) & 1;
        gru_step_frag<<<dim3(256), blk, 0, stream>>>(
            h_bf + (size_t)cur * MS * H_, h_bf + (size_t)nxt * MS * H_,
            h32 + (size_t)cur * MS * H_, h32 + (size_t)nxt * MS * H_,
            wfragf, wfragb, bhh_f, bhh_b, xg_f, xg_b,
            gin_bf, lengths, s);
    }

    // ---- pooled linear head ----
    mean_pool2<<<dim3((B_ * H2) / 256), blk, 0, stream>>>(gin_bf, lengths, gmean_bf);
    gemm_bt<<<dim3(H_ / 128, B_ / 128), blk, 0, stream>>>(
        gmean_bf, H2, wred_bf, H2, b_red, out, OUTC, H2, 0);

    // ---- conv: repack taps (xg dead), one big 256^2 GEMM -> fp16 partials ----
    repack_tap<<<dim3((2 * NF_ * H2) / 256), blk, 0, stream>>>(cw2, wtap_bf, 2);
    repack_tap<<<dim3((3 * NF_ * H2) / 256), blk, 0, stream>>>(cw3, wtap_bf + (size_t)2 * NF_ * H2, 3);
    repack_tap<<<dim3((4 * NF_ * H2) / 256), blk, 0, stream>>>(cw4, wtap_bf + (size_t)5 * NF_ * H2, 4);
    gemm256<3><<<dim3(NCAT / 256, (B_ * T_) / 256), dim3(512), 0, stream>>>(
        gin_bf, H2, wtap_bf, H2, nullptr, P, NCAT, H2);

    conv_max<<<dim3((B_ * 1536) / 256), blk, 0, stream>>>(P, cb2, cb3, cb4, out);
    bow_copy<<<dim3((B_ * 2000) / 256), blk, 0, stream>>>(bow, out);
}

// Round 11
// 1034.505 us; speedup vs baseline: 1.2317x; 1.0610x over previous
//
#include <hip/hip_runtime.h>
#include <hip/hip_bf16.h>
#include <math.h>

#define B_ 256
#define T_ 32
#define D_ 500
#define H_ 1024
#define V_ 8000
#define NF_ 512
#define G3H (3*H_)   // 3072
#define H2 (2*H_)    // 2048
#define OUTC (H_ + 3*NF_ + V_)   // 10560
#define KPAD 512     // D_ padded to 512 for 16B-aligned bf16 rows
#define NTAP 9
#define NCAT (NTAP*NF_)  // 4608
#define MS 512           // stacked M for recurrence (fwd 0..255, bwd 256..511)
#define WFRAG_G (64*32*512)   // elements per gate in whh frag layout (1,048,576)

typedef float f32x4 __attribute__((ext_vector_type(4)));
typedef short bf16x8 __attribute__((ext_vector_type(8)));

static __device__ __forceinline__ short f2b(float f) {
    unsigned u = __float_as_uint(f);
    unsigned r = (u + 0x7fffu + ((u >> 16) & 1u)) >> 16;
    return (short)r;
}
static __device__ __forceinline__ float b2f(short s) {
    return __uint_as_float(((unsigned)(unsigned short)s) << 16);
}

// ---------------------------------------------------------------------------
// bf16 MFMA GEMM (m97 structure + XCD swizzle): C[m,n] = sum_k A[m,k]*Bt[n,k]
// mode 0: fp32 C = v + bias[n]; mode 2: bf16 C = bf16(v + bias[n]);
// mode 3: fp16 C = v. Requires gridDim.x*gridDim.y % 8 == 0.
// ---------------------------------------------------------------------------
__global__ __launch_bounds__(256) void gemm_bt(
    const short* __restrict__ A, int lda,
    const short* __restrict__ Bt, int ldb,
    const float* __restrict__ bias,
    void* __restrict__ Cv, int ldc,
    int K, int mode)
{
    __shared__ short As[128 * 32];
    __shared__ short Bs[128 * 32];
    const int tid  = threadIdx.x;
    const int w    = tid >> 6, lane = tid & 63;

    const int nbx = gridDim.x;
    const int nwg = nbx * gridDim.y;
    int flat = blockIdx.y * nbx + blockIdx.x;
    flat = (flat & 7) * (nwg >> 3) + (flat >> 3);
    const int m0 = (flat / nbx) * 128, n0 = (flat % nbx) * 128;

    const int wm   = (w >> 1) * 64, wn = (w & 1) * 64;

    f32x4 acc[4][4];
#pragma unroll
    for (int i = 0; i < 4; ++i)
#pragma unroll
        for (int j = 0; j < 4; ++j) acc[i][j] = (f32x4){0.f, 0.f, 0.f, 0.f};

    const int srow = w * 16 + (lane >> 2);
    const int scol = (lane & 3) * 8;
    const long aoff0 = (long)(m0 + srow) * lda + scol;
    const long aoff1 = (long)(m0 + srow + 64) * lda + scol;
    const long boff0 = (long)(n0 + srow) * ldb + scol;
    const long boff1 = (long)(n0 + srow + 64) * ldb + scol;
    short* lA0 = As + w * 512;        short* lA1 = As + 2048 + w * 512;
    short* lB0 = Bs + w * 512;        short* lB1 = Bs + 2048 + w * 512;

    const int fr = lane & 15, fk = (lane >> 4) * 8;

    for (int kt = 0; kt < K; kt += 32) {
        __builtin_amdgcn_global_load_lds((const __attribute__((address_space(1))) void*)(A + aoff0 + kt),
                                         (__attribute__((address_space(3))) void*)lA0, 16, 0, 0);
        __builtin_amdgcn_global_load_lds((const __attribute__((address_space(1))) void*)(A + aoff1 + kt),
                                         (__attribute__((address_space(3))) void*)lA1, 16, 0, 0);
        __builtin_amdgcn_global_load_lds((const __attribute__((address_space(1))) void*)(Bt + boff0 + kt),
                                         (__attribute__((address_space(3))) void*)lB0, 16, 0, 0);
        __builtin_amdgcn_global_load_lds((const __attribute__((address_space(1))) void*)(Bt + boff1 + kt),
                                         (__attribute__((address_space(3))) void*)lB1, 16, 0, 0);
        __syncthreads();
        bf16x8 af[4], bfv[4];
#pragma unroll
        for (int i = 0; i < 4; ++i) af[i]  = *(const bf16x8*)(As + (wm + i * 16 + fr) * 32 + fk);
#pragma unroll
        for (int j = 0; j < 4; ++j) bfv[j] = *(const bf16x8*)(Bs + (wn + j * 16 + fr) * 32 + fk);
#pragma unroll
        for (int i = 0; i < 4; ++i)
#pragma unroll
            for (int j = 0; j < 4; ++j)
                acc[i][j] = __builtin_amdgcn_mfma_f32_16x16x32_bf16(af[i], bfv[j], acc[i][j], 0, 0, 0);
        __syncthreads();
    }

    const int er = (lane >> 4) * 4;
    const int ec = lane & 15;
#pragma unroll
    for (int i = 0; i < 4; ++i) {
#pragma unroll
        for (int j = 0; j < 4; ++j) {
#pragma unroll
            for (int q = 0; q < 4; ++q) {
                const int m = m0 + wm + i * 16 + er + q;
                const int n = n0 + wn + j * 16 + ec;
                float v = acc[i][j][q];
                if (mode == 0) {
                    ((float*)Cv)[(long)m * ldc + n] = v + bias[n];
                } else if (mode == 2) {
                    ((short*)Cv)[(long)m * ldc + n] = f2b(v + bias[n]);
                } else {
                    ((_Float16*)Cv)[(long)m * ldc + n] = (_Float16)v;
                }
            }
        }
    }
}

// ---------------------------------------------------------------------------
// Repack Whh (fp32 [3H, H]) into global MFMA B-fragment layout.
// ---------------------------------------------------------------------------
__global__ void repack_whh(const float* __restrict__ src, short* __restrict__ dst)
{
    const int idx = blockIdx.x * 256 + threadIdx.x;   // 3*64*32*64 = 393216
    const int l = idx & 63;
    const int kt = (idx >> 6) & 31;
    const int j16 = (idx >> 11) & 63;
    const int g = idx >> 17;
    const long srow = ((long)(g << 10) + (j16 << 4) + (l & 15)) * H_ + kt * 32 + ((l >> 4) << 3);
    short o[8];
#pragma unroll
    for (int e = 0; e < 8; ++e) o[e] = f2b(src[srow + e]);
    *(bf16x8*)&dst[(long)idx * 8] = *(bf16x8*)o;
}

// ---------------------------------------------------------------------------
// One GRU timestep, K-SPLIT for 2 waves/SIMD. 256 blocks x 512 threads.
// Waves 0-3: r7 tile (w = w8&3), kt in [0,16). Waves 4-7: same tiles,
// kt in [16,32) -> partial accs to LDS -> one barrier -> waves 0-3 add +
// run the r7 epilogue unchanged. No other structural change from r7.
// ---------------------------------------------------------------------------
__global__ __launch_bounds__(512) void gru_step_frag(
    const short* __restrict__ hbf_prev, short* __restrict__ hbf_next,
    const float* __restrict__ h32_prev, float* __restrict__ h32_next,
    const short* __restrict__ wfragf, const short* __restrict__ wfragb,
    const float* __restrict__ bhhf, const float* __restrict__ bhhb,
    const short* __restrict__ xgf, const short* __restrict__ xgb,
    short* __restrict__ gout, const int* __restrict__ lengths, int s)
{
    __shared__ f32x4 lacc[4][6][64];   // 24 KB: [tile-wave][chain][lane]
    const int tid = threadIdx.x;
    const int w8 = tid >> 6;           // 0..7
    const int w = w8 & 3;              // tile id (matches r7's w)
    const int khalf = w8 >> 2;         // 0 or 1
    const int lane = tid & 63;
    const int bid = blockIdx.x;
    const int jt = bid & 31;
    const int mtd = bid >> 5;            // 0..7
    const int dir = mtd >> 2, mt = mtd & 3;
    const int m0 = dir * 256 + mt * 64;
    const int j0 = jt * 32;
    const int wm = (w >> 1) * 32, wj = (w & 1) * 16;
    const int tt = dir ? (T_ - 1 - s) : s;

    const short* wfrag = dir ? wfragb : wfragf;
    const float* bhh = dir ? bhhb : bhhf;
    const short* xg  = dir ? xgb : xgf;

    const int fr15 = lane & 15, fk8 = (lane >> 4) * 8;
    const long arow0 = (long)(m0 + wm + fr15) * H_ + fk8 + khalf * 512;
    const long arow1 = arow0 + (long)16 * H_;
    const int j16 = (j0 + wj) >> 4;      // 0..63
    const short* bbase = wfrag + ((long)j16 * 32 + khalf * 16) * 512 + lane * 8;

    f32x4 acc[3][2];
#pragma unroll
    for (int g = 0; g < 3; ++g)
#pragma unroll
        for (int i = 0; i < 2; ++i) acc[g][i] = (f32x4){0.f, 0.f, 0.f, 0.f};

#pragma unroll 4
    for (int kt = 0; kt < 16; ++kt) {
        const bf16x8 af0 = *(const bf16x8*)(hbf_prev + arow0 + kt * 32);
        const bf16x8 af1 = *(const bf16x8*)(hbf_prev + arow1 + kt * 32);
        const bf16x8 b0 = *(const bf16x8*)(bbase + (long)kt * 512);
        const bf16x8 b1 = *(const bf16x8*)(bbase + (long)kt * 512 + WFRAG_G);
        const bf16x8 b2 = *(const bf16x8*)(bbase + (long)kt * 512 + 2 * WFRAG_G);
        acc[0][0] = __builtin_amdgcn_mfma_f32_16x16x32_bf16(af0, b0, acc[0][0], 0, 0, 0);
        acc[0][1] = __builtin_amdgcn_mfma_f32_16x16x32_bf16(af1, b0, acc[0][1], 0, 0, 0);
        acc[1][0] = __builtin_amdgcn_mfma_f32_16x16x32_bf16(af0, b1, acc[1][0], 0, 0, 0);
        acc[1][1] = __builtin_amdgcn_mfma_f32_16x16x32_bf16(af1, b1, acc[1][1], 0, 0, 0);
        acc[2][0] = __builtin_amdgcn_mfma_f32_16x16x32_bf16(af0, b2, acc[2][0], 0, 0, 0);
        acc[2][1] = __builtin_amdgcn_mfma_f32_16x16x32_bf16(af1, b2, acc[2][1], 0, 0, 0);
    }

    if (khalf == 1) {
#pragma unroll
        for (int g = 0; g < 3; ++g)
#pragma unroll
            for (int i = 0; i < 2; ++i)
                lacc[w][g * 2 + i][lane] = acc[g][i];
    }
    __syncthreads();
    if (khalf == 1) return;

#pragma unroll
    for (int g = 0; g < 3; ++g)
#pragma unroll
        for (int i = 0; i < 2; ++i)
            acc[g][i] += lacc[w][g * 2 + i][lane];

    const int er = (lane >> 4) * 4, ec = lane & 15;
    const int jj = j0 + wj + ec;
    const float bhr = bhh[jj], bhz = bhh[H_ + jj], bhn = bhh[2 * H_ + jj];

#pragma unroll
    for (int i = 0; i < 2; ++i) {
#pragma unroll
        for (int q = 0; q < 4; ++q) {
            const int m = m0 + wm + i * 16 + er + q;
            const int b = m & 255;
            const short* xrow = xg + ((long)b * T_ + tt) * G3H;
            const float xr = b2f(xrow[jj]);
            const float xz = b2f(xrow[H_ + jj]);
            const float xn = b2f(xrow[2 * H_ + jj]);
            const float rr = 1.f / (1.f + expf(-(xr + acc[0][i][q] + bhr)));
            const float zz = 1.f / (1.f + expf(-(xz + acc[1][i][q] + bhz)));
            const float nn = tanhf(xn + rr * (acc[2][i][q] + bhn));
            const long hidx = (long)m * H_ + jj;
            const float hp = h32_prev[hidx];
            const float hnew = (1.f - zz) * nn + zz * hp;
            const bool valid = tt < lengths[b];
            const float ho = valid ? hnew : hp;
            h32_next[hidx] = ho;
            hbf_next[hidx] = f2b(ho);
            gout[((long)b * T_ + tt) * H2 + (long)dir * H_ + jj] = valid ? f2b(hnew) : (short)0;
        }
    }
}

// fp32 -> bf16 with optional K padding (c >= Ksrc -> 0)
__global__ void f2b_pad(const float* __restrict__ src, short* __restrict__ dst,
                        int Ksrc, int Kdst)
{
    const int idx = blockIdx.x * 256 + threadIdx.x;
    const int r = idx / Kdst, c = idx % Kdst;
    dst[idx] = (c < Ksrc) ? f2b(src[(long)r * Ksrc + c]) : (short)0;
}

// conv weight repack: dst[k][f][c] = bf16(src[f][c][k]), src [NF_,2H,ws]
__global__ void repack_tap(const float* __restrict__ src, short* __restrict__ dst, int ws)
{
    const int idx = blockIdx.x * 256 + threadIdx.x;
    const int rem = idx % (NF_ * H2);
    const int k = idx / (NF_ * H2);
    const int f = rem >> 11, c = rem & 2047;
    dst[idx] = f2b(src[((long)(f << 11) + c) * ws + k]);
}

// mean over valid timesteps (gout is zero past length), bf16 in, bf16 out
__global__ void mean_pool2(const short* __restrict__ gin,
                           const int* __restrict__ lengths,
                           short* __restrict__ mean_bf)
{
    const int idx = blockIdx.x * 256 + threadIdx.x;   // B*2H
    const int b = idx >> 11, c = idx & 2047;
    float s = 0.f;
#pragma unroll
    for (int t = 0; t < T_; ++t) s += b2f(gin[((long)(b * T_ + t)) * H2 + c]);
    mean_bf[idx] = f2b(s / (float)lengths[b]);
}

// shifted tap-sum + bias + leaky-relu + max over time
__global__ void conv_max(const _Float16* __restrict__ P,
                         const float* __restrict__ cb2, const float* __restrict__ cb3,
                         const float* __restrict__ cb4, float* __restrict__ out)
{
    const int idx = blockIdx.x * 256 + threadIdx.x;   // B*1536
    const int b = idx / 1536, u0 = idx % 1536;
    int Tout, ws, base, f; float bias;
    if (u0 < 512)       { ws = 2; Tout = 33; base = 0;    f = u0;        bias = cb2[f]; }
    else if (u0 < 1024) { ws = 3; Tout = 34; base = 1024; f = u0 - 512;  bias = cb3[f]; }
    else                { ws = 4; Tout = 35; base = 2560; f = u0 - 1024; bias = cb4[f]; }
    const _Float16* Pb = P + (long)b * T_ * NCAT + base + f;
    float m = -INFINITY;
    for (int u = 0; u < Tout; ++u) {
        float s = bias;
        for (int k = 0; k < ws; ++k) {
            const int t = u - (ws - 1) + k;
            if (t >= 0 && t < T_) s += (float)Pb[(long)t * NCAT + k * NF_];
        }
        s = s > 0.f ? s : 0.01f * s;
        m = fmaxf(m, s);
    }
    out[(long)b * OUTC + H_ + u0] = m;
}

__global__ void bow_copy(const float* __restrict__ bow, float* __restrict__ out)
{
    const int idx = blockIdx.x * 256 + threadIdx.x;   // B * 2000 float4s
    const int b = idx / 2000, q = idx % 2000;
    const float4* src = (const float4*)(bow + (long)b * V_);
    float4* dst = (float4*)(out + (long)b * OUTC + H_ + 3 * NF_);
    dst[q] = src[q];
}

extern "C" void kernel_launch(void* const* d_in, const int* in_sizes, int n_in,
                              void* d_out, int out_size, void* d_ws, size_t ws_size,
                              hipStream_t stream)
{
    const float* text    = (const float*)d_in[0];
    const float* bow     = (const float*)d_in[1];
    const int*   lengths = (const int*)  d_in[2];
    const float* Wih_f   = (const float*)d_in[3];
    const float* Whh_f   = (const float*)d_in[4];
    const float* bih_f   = (const float*)d_in[5];
    const float* bhh_f   = (const float*)d_in[6];
    const float* Wih_b   = (const float*)d_in[7];
    const float* Whh_b   = (const float*)d_in[8];
    const float* bih_b   = (const float*)d_in[9];
    const float* bhh_b   = (const float*)d_in[10];
    const float* W_red   = (const float*)d_in[11];
    const float* b_red   = (const float*)d_in[12];
    const float* cw2     = (const float*)d_in[13];
    const float* cb2     = (const float*)d_in[14];
    const float* cw3     = (const float*)d_in[15];
    const float* cb3     = (const float*)d_in[16];
    const float* cw4     = (const float*)d_in[17];
    const float* cb4     = (const float*)d_in[18];
    float* out = (float*)d_out;

    // ---- workspace layout (r7) ----
    char* ws = (char*)d_ws;
    size_t off = 0;
    short* xg_f = (short*)(ws + off); off += (size_t)B_ * T_ * G3H * 2;   // 50.33 MB
    short* xg_b = (short*)(ws + off); off += (size_t)B_ * T_ * G3H * 2;   // 50.33 MB
    _Float16* P    = (_Float16*)(char*)xg_f;                              // overlay (conv phase)
    short* wtap_bf = (short*)((char*)xg_f + (size_t)B_ * T_ * NCAT * 2);  // after P
    short* gin_bf = (short*)(ws + off); off += (size_t)B_ * T_ * H2 * 2;  // 33.55 MB
    short* text_bf = gin_bf;                                              // overlay (proj phase)
    short* wihf_bf = (short*)((char*)gin_bf + (size_t)B_ * T_ * KPAD * 2);
    short* wihb_bf = wihf_bf + (size_t)G3H * KPAD;
    short* wfragf  = (short*)(ws + off); off += (size_t)3 * WFRAG_G * 2;  // 6.3 MB
    short* wfragb  = (short*)(ws + off); off += (size_t)3 * WFRAG_G * 2;  // 6.3 MB
    short* wred_bf = (short*)(ws + off); off += (size_t)H_ * H2 * 2;
    float* h32     = (float*)(ws + off); off += (size_t)2 * MS * H_ * 4;  // ping-pong fp32
    short* h_bf    = (short*)(ws + off); off += (size_t)2 * MS * H_ * 2;  // ping-pong bf16
    short* gmean_bf= (short*)(ws + off); off += (size_t)B_ * H2 * 2;

    const dim3 blk(256);

    // ---- conversions / repacks ----
    f2b_pad<<<dim3((B_ * T_ * KPAD) / 256), blk, 0, stream>>>(text, text_bf, D_, KPAD);
    f2b_pad<<<dim3((G3H * KPAD) / 256), blk, 0, stream>>>(Wih_f, wihf_bf, D_, KPAD);
    f2b_pad<<<dim3((G3H * KPAD) / 256), blk, 0, stream>>>(Wih_b, wihb_bf, D_, KPAD);
    f2b_pad<<<dim3((H_ * H2) / 256), blk, 0, stream>>>(W_red, wred_bf, H2, H2);
    repack_whh<<<dim3(1536), blk, 0, stream>>>(Whh_f, wfragf);
    repack_whh<<<dim3(1536), blk, 0, stream>>>(Whh_b, wfragb);

    // ---- input projections (both directions), m97 128^2 GEMM ----
    gemm_bt<<<dim3(G3H / 128, (B_ * T_) / 128), blk, 0, stream>>>(
        text_bf, KPAD, wihf_bf, KPAD, bih_f, xg_f, G3H, KPAD, 2);
    gemm_bt<<<dim3(G3H / 128, (B_ * T_) / 128), blk, 0, stream>>>(
        text_bf, KPAD, wihb_bf, KPAD, bih_b, xg_b, G3H, KPAD, 2);

    // ---- stacked bidirectional recurrence: 32 per-step launches ----
    hipMemsetAsync(h32, 0, (size_t)MS * H_ * 4, stream);   // h32 buf0 = 0
    hipMemsetAsync(h_bf, 0, (size_t)MS * H_ * 2, stream);  // h_bf buf0 = 0
    for (int s = 0; s < T_; ++s) {
        const int cur = s & 1, nxt = (s + 1) & 1;
        gru_step_frag<<<dim3(256), dim3(512), 0, stream>>>(
            h_bf + (size_t)cur * MS * H_, h_bf + (size_t)nxt * MS * H_,
            h32 + (size_t)cur * MS * H_, h32 + (size_t)nxt * MS * H_,
            wfragf, wfragb, bhh_f, bhh_b, xg_f, xg_b,
            gin_bf, lengths, s);
    }

    // ---- pooled linear head ----
    mean_pool2<<<dim3((B_ * H2) / 256), blk, 0, stream>>>(gin_bf, lengths, gmean_bf);
    gemm_bt<<<dim3(H_ / 128, B_ / 128), blk, 0, stream>>>(
        gmean_bf, H2, wred_bf, H2, b_red, out, OUTC, H2, 0);

    // ---- conv: repack taps (xg dead), one big GEMM -> fp16 partials ----
    repack_tap<<<dim3((2 * NF_ * H2) / 256), blk, 0, stream>>>(cw2, wtap_bf, 2);
    repack_tap<<<dim3((3 * NF_ * H2) / 256), blk, 0, stream>>>(cw3, wtap_bf + (size_t)2 * NF_ * H2, 3);
    repack_tap<<<dim3((4 * NF_ * H2) / 256), blk, 0, stream>>>(cw4, wtap_bf + (size_t)5 * NF_ * H2, 4);
    gemm_bt<<<dim3(NCAT / 128, (B_ * T_) / 128), blk, 0, stream>>>(
        gin_bf, H2, wtap_bf, H2, nullptr, P, NCAT, H2, 3);

    conv_max<<<dim3((B_ * 1536) / 256), blk, 0, stream>>>(P, cb2, cb3, cb4, out);
    bow_copy<<<dim3((B_ * 2000) / 256), blk, 0, stream>>>(bow, out);
}